// Round 2
// baseline (551.731 us; speedup 1.0000x reference)
//
#include <hip/hip_runtime.h>

// out[s,:] = mean_{e: sid[e]==s} vals[gidx[e],:], D=64 fp32, sids sorted.
//
// R2: TWO-PHASE gather, split by table half, to kill L3 reuse-misses.
//   Evidence: R1 doubled per-wave MLP -> zero change => per-CU outstanding
//   miss capacity saturated; throughput = capacity / avg_latency. 505MB of
//   the 1.02GB delivered misses to HBM, but unique lines are only 246MB:
//   ~260MB are REUSE misses (4x row reuse spread over the whole dispatch,
//   256MB working set == 256MB L3 + stream interference).
//   Phase 0 (separate launch, grid-wide temporal separation): accumulate only
//   edges with gidx in [0, N/2); working set 128MB -> L3-resident -> reuses
//   hit. Stores raw partial sums to out (PLAIN store: stays cached for p1).
//   Phase 1: edges with gidx in [N/2, inf); adds p0 partial, divides, NT-store.
//   Out-of-half edges: branchless clamp to hot row rowLo (L1-resident, free)
//   + mask-multiply to zero. Keeps the 4-loads-in-flight structure intact.
//
// Wave layout: lane = (sub, c): sub=lane>>4 -> one of 4 edges per load inst,
// c=lane&15 -> float4 column. One dwordx4 load = 4 full 256B rows = 4 edges.
// ROW STRIDE = 64 floats * 4B = 256B -> byte offset is idx<<8.
#define D 64

typedef float vfloat4 __attribute__((ext_vector_type(4)));

// starts[s] = first edge index with sids[e] >= s, s in [0, nseg].
__global__ __launch_bounds__(256) void seg_starts_kernel(
    const int* __restrict__ sids, int E, int nseg, int* __restrict__ starts) {
    int e = blockIdx.x * blockDim.x + threadIdx.x;
    if (e >= E) return;
    int cur = __builtin_nontemporal_load(&sids[e]);
    int prev = (e == 0) ? -1 : __builtin_nontemporal_load(&sids[e - 1]);
    for (int s = prev + 1; s <= cur; ++s) starts[s] = e;
    if (e == E - 1) {
        for (int s = cur + 1; s <= nseg; ++s) starts[s] = E;
    }
}

// One wave per segment; accumulates only rows with gidx in [rowLo, rowHi).
// PHASE 0: out[seg] = partial sum (plain store, stays in cache).
// PHASE 1: out[seg] = (out[seg] + partial) / max(cnt,1)  (NT store).
template <int PHASE>
__global__ __launch_bounds__(256) void seg_mean_phase_kernel(
    const float* __restrict__ vals, const int* __restrict__ gidx,
    const int* __restrict__ sids, const int* __restrict__ starts,
    float* __restrict__ out, int E, int nseg, int rowLo, int rowHi) {
    int lane = threadIdx.x & 63;
    int seg = blockIdx.x * (blockDim.x >> 6) + (threadIdx.x >> 6);
    if (seg >= nseg) return;
    int sub = lane >> 4;          // edge subgroup 0..3
    int c16 = (lane & 15) << 4;   // float4 column byte offset 0..240

    int start, end;
    if (starts) {
        start = starts[seg];
        end   = starts[seg + 1];
    } else {
        int lo = 0, hi = E;
        while (lo < hi) { int m = (lo + hi) >> 1; if (sids[m] < seg) lo = m + 1; else hi = m; }
        start = lo;
        int lo2 = start, hi2 = E;
        while (lo2 < hi2) { int m = (lo2 + hi2) >> 1; if (sids[m] < seg + 1) lo2 = m + 1; else hi2 = m; }
        end = lo2;
    }
    int cnt = end - start;

    const char* vbase = (const char*)vals;  // 256MB table: 32-bit byte offsets fit
    unsigned span = (unsigned)(rowHi - rowLo);
    vfloat4 a0 = {0,0,0,0}, a1 = {0,0,0,0}, a2 = {0,0,0,0}, a3 = {0,0,0,0};

    for (int base = start; base < end; base += 64) {
        int n = end - base;
        if (n > 64) n = 64;
        // Coalesced idx load, clamped (branchless).
        int l = (lane < n) ? lane : (n - 1);
        int my = __builtin_nontemporal_load(&gidx[base + l]);

        int j = 0;
        // Main: 16 edges per pass, 4 independent loads in flight.
        for (; j + 16 <= n; j += 16) {
            int i0 = __shfl(my, j +  0 + sub, 64);
            int i1 = __shfl(my, j +  4 + sub, 64);
            int i2 = __shfl(my, j +  8 + sub, 64);
            int i3 = __shfl(my, j + 12 + sub, 64);
            // In-half? (uniform within each 16-lane subgroup)
            bool h0 = (unsigned)(i0 - rowLo) < span;
            bool h1 = (unsigned)(i1 - rowLo) < span;
            bool h2 = (unsigned)(i2 - rowLo) < span;
            bool h3 = (unsigned)(i3 - rowLo) < span;
            // Out-of-half -> clamp to hot row rowLo (stays L1-resident, ~free).
            int p0 = h0 ? i0 : rowLo;
            int p1 = h1 ? i1 : rowLo;
            int p2 = h2 ? i2 : rowLo;
            int p3 = h3 ? i3 : rowLo;
            vfloat4 v0 = *(const vfloat4*)(vbase + (((unsigned)p0 << 8) | c16));
            vfloat4 v1 = *(const vfloat4*)(vbase + (((unsigned)p1 << 8) | c16));
            vfloat4 v2 = *(const vfloat4*)(vbase + (((unsigned)p2 << 8) | c16));
            vfloat4 v3 = *(const vfloat4*)(vbase + (((unsigned)p3 << 8) | c16));
            a0 += v0 * (h0 ? 1.0f : 0.0f);
            a1 += v1 * (h1 ? 1.0f : 0.0f);
            a2 += v2 * (h2 ? 1.0f : 0.0f);
            a3 += v3 * (h3 ? 1.0f : 0.0f);
        }
        // Remainder (<16 edges): predicated pass; invalid/out-of-half -> 0.
        if (j < n) {
            int e0 = j + sub, e1 = j + 4 + sub, e2 = j + 8 + sub, e3 = j + 12 + sub;
            int s0 = (e0 < n) ? e0 : (n - 1);
            int s1 = (e1 < n) ? e1 : (n - 1);
            int s2 = (e2 < n) ? e2 : (n - 1);
            int s3 = (e3 < n) ? e3 : (n - 1);
            int i0 = __shfl(my, s0, 64);
            int i1 = __shfl(my, s1, 64);
            int i2 = __shfl(my, s2, 64);
            int i3 = __shfl(my, s3, 64);
            bool h0 = ((unsigned)(i0 - rowLo) < span) && (e0 < n);
            bool h1 = ((unsigned)(i1 - rowLo) < span) && (e1 < n);
            bool h2 = ((unsigned)(i2 - rowLo) < span) && (e2 < n);
            bool h3 = ((unsigned)(i3 - rowLo) < span) && (e3 < n);
            int p0 = h0 ? i0 : rowLo;
            int p1 = h1 ? i1 : rowLo;
            int p2 = h2 ? i2 : rowLo;
            int p3 = h3 ? i3 : rowLo;
            vfloat4 v0 = *(const vfloat4*)(vbase + (((unsigned)p0 << 8) | c16));
            vfloat4 v1 = *(const vfloat4*)(vbase + (((unsigned)p1 << 8) | c16));
            vfloat4 v2 = *(const vfloat4*)(vbase + (((unsigned)p2 << 8) | c16));
            vfloat4 v3 = *(const vfloat4*)(vbase + (((unsigned)p3 << 8) | c16));
            a0 += v0 * (h0 ? 1.0f : 0.0f);
            a1 += v1 * (h1 ? 1.0f : 0.0f);
            a2 += v2 * (h2 ? 1.0f : 0.0f);
            a3 += v3 * (h3 ? 1.0f : 0.0f);
        }
    }

    a0 += a1; a2 += a3; a0 += a2;
    // Reduce across the 4 edge subgroups (lane bits 4,5).
    a0.x += __shfl_xor(a0.x, 16, 64); a0.y += __shfl_xor(a0.y, 16, 64);
    a0.z += __shfl_xor(a0.z, 16, 64); a0.w += __shfl_xor(a0.w, 16, 64);
    a0.x += __shfl_xor(a0.x, 32, 64); a0.y += __shfl_xor(a0.y, 32, 64);
    a0.z += __shfl_xor(a0.z, 32, 64); a0.w += __shfl_xor(a0.w, 32, 64);

    if (sub == 0) {
        char* op = (char*)out + (((unsigned)seg << 8) | c16);
        if (PHASE == 0) {
            // Raw partial sum; PLAIN store so it stays cached for phase 1
            // (same block id -> likely same XCD -> L2 hit on the re-read).
            *(vfloat4*)op = a0;
        } else {
            vfloat4 prev = *(const vfloat4*)op;
            float inv = 1.0f / (float)((cnt > 0) ? cnt : 1);
            vfloat4 r = (prev + a0) * inv;
            // 16 lanes x 16B = one 256B out row; NT store: never read again.
            __builtin_nontemporal_store(r, (vfloat4*)op);
        }
    }
}

extern "C" void kernel_launch(void* const* d_in, const int* in_sizes, int n_in,
                              void* d_out, int out_size, void* d_ws, size_t ws_size,
                              hipStream_t stream) {
    const float* vals = (const float*)d_in[0];   // [N_SRC, 64] fp32
    const int*   gidx = (const int*)d_in[1];     // [E] int32
    const int*   sids = (const int*)d_in[2];     // [E] int32, sorted
    float*       out  = (float*)d_out;           // [nseg, 64] fp32

    int E = in_sizes[1];
    int nseg = out_size / D;
    int nsrc_rows = in_sizes[0] / D;             // element-count semantics
    int Nh = nsrc_rows >> 1;
    if (Nh < 1) Nh = 1;
    // Correctness does NOT depend on Nh: phase0 covers [0,Nh), phase1
    // [Nh, INT_MAX) — union is all indices even if nsrc estimate is off.

    int* starts = nullptr;
    size_t need = (size_t)(nseg + 1) * sizeof(int);
    if (ws_size >= need) {
        starts = (int*)d_ws;
        int blocks = (E + 255) / 256;
        seg_starts_kernel<<<blocks, 256, 0, stream>>>(sids, E, nseg, starts);
    }

    const int waves_per_block = 4;
    int blocks2 = (nseg + waves_per_block - 1) / waves_per_block;
    seg_mean_phase_kernel<0><<<blocks2, waves_per_block * 64, 0, stream>>>(
        vals, gidx, sids, starts, out, E, nseg, 0, Nh);
    seg_mean_phase_kernel<1><<<blocks2, waves_per_block * 64, 0, stream>>>(
        vals, gidx, sids, starts, out, E, nseg, Nh, 0x7fffffff);
}

// Round 3
// 466.586 us; speedup vs baseline: 1.1825x; 1.1825x over previous
//
#include <hip/hip_runtime.h>

// out[s,:] = mean_{e: sid[e]==s} vals[gidx[e],:], D=64 fp32, sids sorted.
// Wave layout: lane = (sub, c): sub=lane>>4 -> one of 4 edges per load inst,
// c=lane&15 -> float4 column. One dwordx4 load = 4 full 256B rows = 4 edges.
// ROW STRIDE = 64 floats * 4B = 256B -> byte offset is idx<<8.
// Streaming data (gidx, out) uses non-temporal hints so the 256MB table keeps
// the 256MB L3; table loads stay cached (4x average reuse).
//
// R3 note (roofline evidence): delivered-to-CU bytes = 4M edges * 256B +
// 16MB idx = 1.04GB in 184us = 5.6 TB/s, vs 6.7 TB/s best streaming observed
// on-chip. R1 (2x per-wave MLP) and R2 (two-phase L3-resident working set)
// both left delivered throughput unchanged => the kernel sits at the
// random-256B-granule delivery ceiling, not latency- or issue-bound.
// This round: revert R2's two-phase split (regression, +90us = extra pass's
// issue floor); keep single-pass R0 structure. Only change: starts kernel
// uses shfl_up instead of a duplicate sids[e-1] load (halves its 32MB read).
#define D 64

// Native vector type: __builtin_nontemporal_* requires scalar/native-vector,
// not HIP's struct-based float4.
typedef float vfloat4 __attribute__((ext_vector_type(4)));

// starts[s] = first edge index with sids[e] >= s, s in [0, nseg].
// Neighbor value via shfl_up; only lane 0 of each wave re-loads sids[e-1].
__global__ __launch_bounds__(256) void seg_starts_kernel(
    const int* __restrict__ sids, int E, int nseg, int* __restrict__ starts) {
    int e = blockIdx.x * blockDim.x + threadIdx.x;
    int lane = threadIdx.x & 63;
    int cur = (e < E) ? __builtin_nontemporal_load(&sids[e]) : 0;
    int prev = __shfl_up(cur, 1, 64);
    if (lane == 0) prev = (e == 0) ? -1 : __builtin_nontemporal_load(&sids[e - 1]);
    if (e >= E) return;
    for (int s = prev + 1; s <= cur; ++s) starts[s] = e;
    if (e == E - 1) {
        for (int s = cur + 1; s <= nseg; ++s) starts[s] = E;
    }
}

// One wave per segment. starts==nullptr -> in-kernel binary search fallback
// (only when ws_size can't hold the starts array).
__global__ __launch_bounds__(256) void seg_mean_kernel(
    const float* __restrict__ vals, const int* __restrict__ gidx,
    const int* __restrict__ sids, const int* __restrict__ starts,
    float* __restrict__ out, int E, int nseg) {
    int lane = threadIdx.x & 63;
    int seg = blockIdx.x * (blockDim.x >> 6) + (threadIdx.x >> 6);
    if (seg >= nseg) return;
    int sub = lane >> 4;          // edge subgroup 0..3
    int c16 = (lane & 15) << 4;   // float4 column byte offset 0..240

    int start, end;
    if (starts) {
        start = starts[seg];
        end   = starts[seg + 1];
    } else {
        int lo = 0, hi = E;
        while (lo < hi) { int m = (lo + hi) >> 1; if (sids[m] < seg) lo = m + 1; else hi = m; }
        start = lo;
        int lo2 = start, hi2 = E;
        while (lo2 < hi2) { int m = (lo2 + hi2) >> 1; if (sids[m] < seg + 1) lo2 = m + 1; else hi2 = m; }
        end = lo2;
    }
    int cnt = end - start;

    const char* vbase = (const char*)vals;  // 256MB table: 32-bit byte offsets fit
    vfloat4 a0 = {0,0,0,0}, a1 = {0,0,0,0}, a2 = {0,0,0,0}, a3 = {0,0,0,0};

    for (int base = start; base < end; base += 64) {
        int n = end - base;
        if (n > 64) n = 64;
        // Coalesced idx load, clamped (branchless).
        int l = (lane < n) ? lane : (n - 1);
        int my = __builtin_nontemporal_load(&gidx[base + l]);

        int j = 0;
        // Main: 16 edges per pass, 4 independent 1KB loads in flight.
        for (; j + 16 <= n; j += 16) {
            int i0 = __shfl(my, j +  0 + sub, 64);
            int i1 = __shfl(my, j +  4 + sub, 64);
            int i2 = __shfl(my, j +  8 + sub, 64);
            int i3 = __shfl(my, j + 12 + sub, 64);
            vfloat4 v0 = *(const vfloat4*)(vbase + (((unsigned)i0 << 8) | c16));
            vfloat4 v1 = *(const vfloat4*)(vbase + (((unsigned)i1 << 8) | c16));
            vfloat4 v2 = *(const vfloat4*)(vbase + (((unsigned)i2 << 8) | c16));
            vfloat4 v3 = *(const vfloat4*)(vbase + (((unsigned)i3 << 8) | c16));
            a0 += v0; a1 += v1; a2 += v2; a3 += v3;
        }
        // Remainder (<16 edges): one branchless predicated pass, 4 loads in
        // flight, clamped shfl lane + mask-mul (invalid edges contribute 0).
        if (j < n) {
            int e0 = j + sub, e1 = j + 4 + sub, e2 = j + 8 + sub, e3 = j + 12 + sub;
            int s0 = (e0 < n) ? e0 : (n - 1);
            int s1 = (e1 < n) ? e1 : (n - 1);
            int s2 = (e2 < n) ? e2 : (n - 1);
            int s3 = (e3 < n) ? e3 : (n - 1);
            int i0 = __shfl(my, s0, 64);
            int i1 = __shfl(my, s1, 64);
            int i2 = __shfl(my, s2, 64);
            int i3 = __shfl(my, s3, 64);
            vfloat4 v0 = *(const vfloat4*)(vbase + (((unsigned)i0 << 8) | c16));
            vfloat4 v1 = *(const vfloat4*)(vbase + (((unsigned)i1 << 8) | c16));
            vfloat4 v2 = *(const vfloat4*)(vbase + (((unsigned)i2 << 8) | c16));
            vfloat4 v3 = *(const vfloat4*)(vbase + (((unsigned)i3 << 8) | c16));
            a0 += v0 * ((e0 < n) ? 1.0f : 0.0f);
            a1 += v1 * ((e1 < n) ? 1.0f : 0.0f);
            a2 += v2 * ((e2 < n) ? 1.0f : 0.0f);
            a3 += v3 * ((e3 < n) ? 1.0f : 0.0f);
        }
    }

    a0 += a1; a2 += a3; a0 += a2;
    // Reduce across the 4 edge subgroups (lane bits 4,5).
    a0.x += __shfl_xor(a0.x, 16, 64); a0.y += __shfl_xor(a0.y, 16, 64);
    a0.z += __shfl_xor(a0.z, 16, 64); a0.w += __shfl_xor(a0.w, 16, 64);
    a0.x += __shfl_xor(a0.x, 32, 64); a0.y += __shfl_xor(a0.y, 32, 64);
    a0.z += __shfl_xor(a0.z, 32, 64); a0.w += __shfl_xor(a0.w, 32, 64);

    float inv = 1.0f / (float)((cnt > 0) ? cnt : 1);
    if (sub == 0) {
        vfloat4 r = a0 * inv;
        // 16 lanes x 16B = one 256B out row; NT store: written once, never read.
        __builtin_nontemporal_store(r, (vfloat4*)((char*)out + (((unsigned)seg << 8) | c16)));
    }
}

extern "C" void kernel_launch(void* const* d_in, const int* in_sizes, int n_in,
                              void* d_out, int out_size, void* d_ws, size_t ws_size,
                              hipStream_t stream) {
    const float* vals = (const float*)d_in[0];   // [N_SRC, 64] fp32
    const int*   gidx = (const int*)d_in[1];     // [E] int32
    const int*   sids = (const int*)d_in[2];     // [E] int32, sorted
    float*       out  = (float*)d_out;           // [nseg, 64] fp32

    int E = in_sizes[1];
    int nseg = out_size / D;

    int* starts = nullptr;
    size_t need = (size_t)(nseg + 1) * sizeof(int);
    if (ws_size >= need) {
        starts = (int*)d_ws;
        int blocks = (E + 255) / 256;
        seg_starts_kernel<<<blocks, 256, 0, stream>>>(sids, E, nseg, starts);
    }

    const int waves_per_block = 4;
    int blocks2 = (nseg + waves_per_block - 1) / waves_per_block;
    seg_mean_kernel<<<blocks2, waves_per_block * 64, 0, stream>>>(
        vals, gidx, sids, starts, out, E, nseg);
}